// Round 9
// baseline (138.866 us; speedup 1.0000x reference)
//
#include <hip/hip_runtime.h>
#include <hip/hip_bf16.h>

// Block-diagonal matmul: out[t, n*64+e] = sum_d inp[t, n*64+d] * blocks[n, d, e]
// T=16384, 64 blocks of 64x64, fp32 in/out, bf16 MFMA compute.
//
// Round 9: R8 (NT stores, zero LDS/barriers) + max TLP with NO read duplication.
//  Split by strips (not output halves, which duplicated reads in R7):
//  8192 waves, each owns block n = wid/128 and 8 strips (wid%128) + 128k.
//  Full-block weights per wave (compiler keeps them L1-hot if it sinks the
//  gather; R8 compiled at 36 VGPR). Grid 2048 @ __launch_bounds__(256,8)
//  -> exactly 8 WG/CU = 32 waves/CU, single uniform round.

typedef __attribute__((ext_vector_type(8))) short short8;   // 8 bf16
typedef __attribute__((ext_vector_type(4))) float f32x4;

#define D_TOT 4096
#define NK    8
#define STEP  ((size_t)128 * 16 * D_TOT)   // 128 strip-slots * 16 rows * 4096

__device__ __forceinline__ short f2b(float x) {
    union { __hip_bfloat16 h; short s; } u;
    u.h = __float2bfloat16(x);
    return u.s;
}

__device__ __forceinline__ short8 cvt8(f32x4 lo, f32x4 hi) {
    short8 a;
    a[0]=f2b(lo[0]); a[1]=f2b(lo[1]); a[2]=f2b(lo[2]); a[3]=f2b(lo[3]);
    a[4]=f2b(hi[0]); a[5]=f2b(hi[1]); a[6]=f2b(hi[2]); a[7]=f2b(hi[3]);
    return a;
}

__global__ __launch_bounds__(256, 8) void block_linear_kernel(
    const float* __restrict__ inp,
    const float* __restrict__ blocks,
    float* __restrict__ out)
{
    const int tid  = threadIdx.x;
    const int wid  = blockIdx.x * 4 + (tid >> 6);   // global wave 0..8191
    const int lane = tid & 63;
    const int g    = lane >> 4;         // k-group
    const int lr   = lane & 15;         // row-within-strip / e-frag index

    const int n  = wid >> 7;            // block index (128 waves per block)
    const int s0 = wid & 127;           // strip slot; strips = s0 + 128k

    // ---- weights -> registers (one-time gather; L1/L2-hot) ----
    // frag (nt,s): lane (g,lr) holds W[d = s*32+8g+i][e = nt*16+lr], i=0..7
    const float* Wn = blocks + (size_t)n * 4096;
    short8 wf[4][2];
    #pragma unroll
    for (int nt = 0; nt < 4; ++nt)
        #pragma unroll
        for (int s = 0; s < 2; ++s) {
            short8 a;
            #pragma unroll
            for (int i = 0; i < 8; ++i)
                a[i] = f2b(Wn[(s * 32 + 8 * g + i) * 64 + nt * 16 + lr]);
            wf[nt][s] = a;
        }

    const float* gin = inp + (size_t)(s0 * 16 + lr) * D_TOT + n * 64 + 8 * g;
    float*      gout = out + (size_t)(s0 * 16 + lr) * D_TOT + n * 64 + g * 4;

    #pragma unroll 1
    for (int k = 0; k < NK; ++k) {
        const float* p = gin + (size_t)k * STEP;
        f32x4 a0 = *(const f32x4*)(p);
        f32x4 a1 = *(const f32x4*)(p + 4);
        f32x4 a2 = *(const f32x4*)(p + 32);
        f32x4 a3 = *(const f32x4*)(p + 36);

        short8 b0 = cvt8(a0, a1);       // k = 0..31 of this lane's row
        short8 b1 = cvt8(a2, a3);       // k = 32..63

        float* go = gout + (size_t)k * STEP;
        #pragma unroll
        for (int nt = 0; nt < 4; ++nt) {
            f32x4 acc = (f32x4){0.f, 0.f, 0.f, 0.f};
            acc = __builtin_amdgcn_mfma_f32_16x16x32_bf16(wf[nt][0], b0, acc, 0, 0, 0);
            acc = __builtin_amdgcn_mfma_f32_16x16x32_bf16(wf[nt][1], b1, acc, 0, 0, 0);
            // lane (g,lr) reg j -> out[row][n*64 + nt*16 + g*4 + j]
            __builtin_nontemporal_store(acc, (f32x4*)(go + nt * 16));
        }
    }
}

extern "C" void kernel_launch(void* const* d_in, const int* in_sizes, int n_in,
                              void* d_out, int out_size, void* d_ws, size_t ws_size,
                              hipStream_t stream) {
    const float* inp    = (const float*)d_in[0];
    const float* blocks = (const float*)d_in[1];
    float* out          = (float*)d_out;

    block_linear_kernel<<<2048, 256, 0, stream>>>(inp, blocks, out);
}

// Round 10
// 118.125 us; speedup vs baseline: 1.1756x; 1.1756x over previous
//
#include <hip/hip_runtime.h>
#include <hip/hip_bf16.h>

// Block-diagonal matmul: out[t, n*64+e] = sum_d inp[t, n*64+d] * blocks[n, d, e]
// T=16384, 64 blocks of 64x64, fp32 in/out, bf16 MFMA compute.
//
// Round 10: DRAM page-locality design. R8 (best, 117us @3.73 TB/s eff) visits
// each 16KB-strided row with only 256B per k-step. Here each wave processes 4
// CONSECUTIVE blocks for its rows -> 1KB-per-row back-to-back load bursts and
// ~1KB-per-row store bursts (memory-controller page batching x4), with zero
// read duplication. 4 blocks' weights live frag-ordered in LDS (32KB, staged
// once, R3-validated permutation); input global->reg; NT stores (R8 win).
// Grid 64x16 = 1024 WGs @ (256,4) = 4 WG/CU (R8's winning occupancy).
// Wave w of WG(slab,ngrp): strips s = slab*16 + w*4 + k, k=0..3; cols
// ngrp*1024 .. +1024 (blocks ngrp*4 .. +3).

typedef __attribute__((ext_vector_type(8))) short short8;   // 8 bf16
typedef __attribute__((ext_vector_type(4))) float f32x4;

#define D_TOT 4096
#define NK    4

__device__ __forceinline__ short f2b(float x) {
    union { __hip_bfloat16 h; short s; } u;
    u.h = __float2bfloat16(x);
    return u.s;
}

__device__ __forceinline__ short8 cvt8(f32x4 lo, f32x4 hi) {
    short8 a;
    a[0]=f2b(lo[0]); a[1]=f2b(lo[1]); a[2]=f2b(lo[2]); a[3]=f2b(lo[3]);
    a[4]=f2b(hi[0]); a[5]=f2b(hi[1]); a[6]=f2b(hi[2]); a[7]=f2b(hi[3]);
    return a;
}

__global__ __launch_bounds__(256, 4) void block_linear_kernel(
    const float* __restrict__ inp,
    const float* __restrict__ blocks,
    float* __restrict__ out)
{
    __shared__ __align__(16) __hip_bfloat16 WF[4 * 4096];   // 4 blocks, frag-ordered

    const int slab = blockIdx.x;        // 0..63
    const int ngrp = blockIdx.y;        // 0..15 : group of 4 consecutive blocks
    const int tid  = threadIdx.x;
    const int w    = tid >> 6;
    const int lane = tid & 63;
    const int g    = lane >> 4;         // k-group
    const int lr   = lane & 15;         // row-within-strip / e-frag index

    // ---- stage 4 blocks' weights into LDS, MFMA A-fragment order (R3 recipe) ----
    // frag (b,nt,s): lane l holds W_b[d = s*32+8*(l>>4)+i][e = nt*16+(l&15)]
    const float* Wg = blocks + (size_t)ngrp * 4 * 4096;
    #pragma unroll
    for (int i = 0; i < 64; ++i) {
        int flat = tid + 256 * i;              // 0..16383 (coalesced read)
        int b = flat >> 12, idx = flat & 4095;
        int d = idx >> 6, e = idx & 63;
        int dst = b * 4096
                + (((e >> 4) * 2 + (d >> 5)) * 64 + ((d >> 3) & 3) * 16 + (e & 15)) * 8
                + (d & 7);
        WF[dst] = __float2bfloat16(Wg[flat]);
    }
    __syncthreads();

    #pragma unroll 1
    for (int k = 0; k < NK; ++k) {
        const int s = slab * 16 + w * 4 + k;             // strip 0..1023
        const float* rp = inp + (size_t)(s * 16 + lr) * D_TOT + ngrp * 256 + 8 * g;
        float*       go = out + (size_t)(s * 16 + lr) * D_TOT + ngrp * 256 + g * 4;

        // ---- 16 loads back-to-back: each row gets 1KB in one burst ----
        f32x4 L[4][4];
        #pragma unroll
        for (int b = 0; b < 4; ++b) {
            const float* p = rp + b * 64;
            L[b][0] = *(const f32x4*)(p);
            L[b][1] = *(const f32x4*)(p + 4);
            L[b][2] = *(const f32x4*)(p + 32);
            L[b][3] = *(const f32x4*)(p + 36);
        }
        __builtin_amdgcn_sched_barrier(0);   // all 16 issued before compute

        // ---- per block: cvt, A-frags from LDS, MFMA, NT store ----
        #pragma unroll
        for (int b = 0; b < 4; ++b) {
            short8 b0 = cvt8(L[b][0], L[b][1]);    // k = 0..31 of this lane's row
            short8 b1 = cvt8(L[b][2], L[b][3]);    // k = 32..63
            #pragma unroll
            for (int nt = 0; nt < 4; ++nt) {
                short8 a0 = *(const short8*)&WF[b * 4096 + ((nt * 2 + 0) * 64 + lane) * 8];
                short8 a1 = *(const short8*)&WF[b * 4096 + ((nt * 2 + 1) * 64 + lane) * 8];
                f32x4 acc = (f32x4){0.f, 0.f, 0.f, 0.f};
                acc = __builtin_amdgcn_mfma_f32_16x16x32_bf16(a0, b0, acc, 0, 0, 0);
                acc = __builtin_amdgcn_mfma_f32_16x16x32_bf16(a1, b1, acc, 0, 0, 0);
                // lane (g,lr) reg j -> out[row][ngrp*256 + b*64 + nt*16 + g*4 + j]
                __builtin_nontemporal_store(acc, (f32x4*)(go + b * 64 + nt * 16));
            }
        }
    }
}

extern "C" void kernel_launch(void* const* d_in, const int* in_sizes, int n_in,
                              void* d_out, int out_size, void* d_ws, size_t ws_size,
                              hipStream_t stream) {
    const float* inp    = (const float*)d_in[0];
    const float* blocks = (const float*)d_in[1];
    float* out          = (float*)d_out;

    dim3 grid(64, 16);   // 64 strip-slabs x 16 block-groups
    block_linear_kernel<<<grid, 256, 0, stream>>>(inp, blocks, out);
}

// Round 11
// 101.658 us; speedup vs baseline: 1.3660x; 1.1620x over previous
//
#include <hip/hip_runtime.h>
#include <hip/hip_bf16.h>

// Block-diagonal matmul: out[t, n*64+e] = sum_d inp[t, n*64+d] * blocks[n, d, e]
// T=16384, 64 blocks of 64x64, fp32 in/out, bf16 MFMA compute.
//
// Round 11: synthesis = NT stores (R8) + 1KB-contiguous bursts both ways (R10)
// + zero write amplification via LDS bounce (R4).
//  - WG = 512 thr (8 waves): 4-block group (1KB col span) x 512 rows, 16 tiles
//    of 32 rows. Wave w: block b=w&3, row-half rg=w>>2.
//  - loads: 1 instr = 1 row x 1KB (lane l -> col 4l), reg pf, cvt bf16,
//    XOR-swizzled INB; compute reads conflict-free b128 frags (R4-validated).
//  - stores: acc -> swizzled OUTB -> row-linear readback -> NT 1KB-contiguous
//    global_store_dwordx4 (full-line, no amplification).
//  - weights in regs per wave (R2-validated frag recipe); 2 barriers/tile.
//  - LDS 48KB, __launch_bounds__(512,2) -> 16 waves/CU; grid 512 = 2/CU exact.

typedef __attribute__((ext_vector_type(8))) short short8;   // 8 bf16
typedef __attribute__((ext_vector_type(4))) short bf16x4;   // 4 bf16
typedef __attribute__((ext_vector_type(4))) float f32x4;

#define D_TOT  4096
#define TROWS  32
#define NTILES 16

__device__ __forceinline__ short f2b(float x) {
    union { __hip_bfloat16 h; short s; } u;
    u.h = __float2bfloat16(x);
    return u.s;
}

__global__ __launch_bounds__(512, 2) void block_linear_kernel(
    const float* __restrict__ inp,
    const float* __restrict__ blocks,
    float* __restrict__ out)
{
    __shared__ __align__(16) unsigned char INB[TROWS * 512];    // bf16 [32][256], swizzled
    __shared__ __align__(16) unsigned char OUTB[TROWS * 1024];  // f32  [32][256], swizzled

    const int slab = blockIdx.x;        // 0..31 : 512-row slab
    const int ngrp = blockIdx.y;        // 0..15 : group of 4 consecutive blocks
    const int tid  = threadIdx.x;
    const int w    = tid >> 6;          // wave 0..7
    const int lane = tid & 63;
    const int g    = lane >> 4;         // k-group
    const int lr   = lane & 15;
    const int rg   = w >> 2;            // row-half (rows rg*16 + lr)
    const int b    = w & 3;             // block within group

    // ---- weights for block ngrp*4+b -> frag registers (one-time, L3-hot) ----
    // frag (nt,s): lane (g,lr) holds W[d = s*32+8g+i][e = nt*16+lr], i=0..7
    const float* Wn = blocks + (size_t)(ngrp * 4 + b) * 4096;
    short8 wf[4][2];
    #pragma unroll
    for (int nt = 0; nt < 4; ++nt)
        #pragma unroll
        for (int s = 0; s < 2; ++s) {
            short8 a;
            #pragma unroll
            for (int i = 0; i < 8; ++i)
                a[i] = f2b(Wn[(s * 32 + 8 * g + i) * 64 + nt * 16 + lr]);
            wf[nt][s] = a;
        }

    const float* gin  = inp + (size_t)slab * 512 * D_TOT + ngrp * 256;
    float*       gout = out + (size_t)slab * 512 * D_TOT + ngrp * 256;

    // ---- prologue: load + stage tile 0 (wave w: rows w, w+8, w+16, w+24) ----
    f32x4 pf[4];
    #pragma unroll
    for (int j = 0; j < 4; ++j)
        pf[j] = *(const f32x4*)(gin + (size_t)(w + 8 * j) * D_TOT + lane * 4);
    #pragma unroll
    for (int j = 0; j < 4; ++j) {
        const int r = w + 8 * j;
        bf16x4 v;
        v[0] = f2b(pf[j][0]); v[1] = f2b(pf[j][1]);
        v[2] = f2b(pf[j][2]); v[3] = f2b(pf[j][3]);
        *(bf16x4*)&INB[r * 512 + (((lane >> 1) ^ (r & 7)) << 4) + ((lane & 1) << 3)] = v;
    }

    for (int t = 0; t < NTILES; ++t) {
        __syncthreads();   // INB(t) ready; OUTB(t-1) fully consumed

        // ---- compute: b-frags from swizzled INB, 8 MFMA -> acc[4] ----
        const int r = rg * 16 + lr;
        short8 bfrag[2];
        #pragma unroll
        for (int s = 0; s < 2; ++s) {
            const int c = b * 8 + s * 4 + g;      // 16B chunk within row
            bfrag[s] = *(const short8*)&INB[r * 512 + ((c ^ (r & 7)) << 4)];
        }
        f32x4 acc[4];
        #pragma unroll
        for (int nt = 0; nt < 4; ++nt) {
            acc[nt] = (f32x4){0.f, 0.f, 0.f, 0.f};
            acc[nt] = __builtin_amdgcn_mfma_f32_16x16x32_bf16(wf[nt][0], bfrag[0], acc[nt], 0, 0, 0);
            acc[nt] = __builtin_amdgcn_mfma_f32_16x16x32_bf16(wf[nt][1], bfrag[1], acc[nt], 0, 0, 0);
        }

        // ---- prefetch tile t+1 (1KB-per-row contiguous instructions) ----
        if (t + 1 < NTILES) {
            const float* gi = gin + (size_t)(t + 1) * TROWS * D_TOT;
            #pragma unroll
            for (int j = 0; j < 4; ++j)
                pf[j] = *(const f32x4*)(gi + (size_t)(w + 8 * j) * D_TOT + lane * 4);
        }

        // ---- acc -> swizzled OUTB ----
        #pragma unroll
        for (int nt = 0; nt < 4; ++nt) {
            const int c = b * 16 + nt * 4 + g;    // 16B chunk 0..63
            *(f32x4*)&OUTB[r * 1024 + ((c ^ (r & 7)) << 4)] = acc[nt];
        }

        __syncthreads();   // OUTB(t) complete; INB(t) free

        // ---- store OUTB row-linear, NT, 1KB/instr + stage INB(t+1) ----
        float* go = gout + (size_t)t * TROWS * D_TOT;
        #pragma unroll
        for (int j = 0; j < 4; ++j) {
            const int r2 = w + 8 * j;
            f32x4 v = *(const f32x4*)&OUTB[r2 * 1024 + ((lane ^ (r2 & 7)) << 4)];
            __builtin_nontemporal_store(v, (f32x4*)(go + (size_t)r2 * D_TOT + lane * 4));
        }
        if (t + 1 < NTILES) {
            #pragma unroll
            for (int j = 0; j < 4; ++j) {
                const int r2 = w + 8 * j;
                bf16x4 v;
                v[0] = f2b(pf[j][0]); v[1] = f2b(pf[j][1]);
                v[2] = f2b(pf[j][2]); v[3] = f2b(pf[j][3]);
                *(bf16x4*)&INB[r2 * 512 + (((lane >> 1) ^ (r2 & 7)) << 4) + ((lane & 1) << 3)] = v;
            }
        }
    }
}

extern "C" void kernel_launch(void* const* d_in, const int* in_sizes, int n_in,
                              void* d_out, int out_size, void* d_ws, size_t ws_size,
                              hipStream_t stream) {
    const float* inp    = (const float*)d_in[0];
    const float* blocks = (const float*)d_in[1];
    float* out          = (float*)d_out;

    dim3 grid(32, 16);   // 32 row-slabs x 16 block-groups = 512 WGs (2/CU exact)
    block_linear_kernel<<<grid, 512, 0, stream>>>(inp, blocks, out);
}